// Round 3
// baseline (420.757 us; speedup 1.0000x reference)
//
#include <hip/hip_runtime.h>
#include <hip/hip_bf16.h>

#define B 8
#define T 1024
#define E 128
#define H 8
#define DH 16
#define E3 384

#define NBLOCKS 512

typedef __attribute__((ext_vector_type(8))) short short8;
typedef __attribute__((ext_vector_type(4))) short short4s;
typedef __attribute__((ext_vector_type(4))) float f32x4;

// fp32 -> bf16 (round-to-nearest-even), bit pattern in a short
static __device__ inline short bf16s(float x) {
    union { float f; unsigned u; } v; v.f = x;
    unsigned r = v.u + 0x7fffu + ((v.u >> 16) & 1u);
    return (short)(r >> 16);
}

// exp2 via the HW transcendental (1 inst)
#if __has_builtin(__builtin_amdgcn_exp2f)
static __device__ inline float fexp2(float x) { return __builtin_amdgcn_exp2f(x); }
#else
static __device__ inline float fexp2(float x) { return __builtin_exp2f(x); }
#endif

// pack two fp32 into bf16x2 via v_cvt_pk_bf16_f32
static __device__ inline __hip_bfloat162 pk2(float a, float b) {
    float2 t; t.x = a; t.y = b;
    return __float22bfloat162_rn(t);
}

#define QSCALE 0.36067376022224085f   /* 0.25 * log2(e) */

// ---------------------------------------------------------------------------
// Hand-rolled grid barrier (Guideline 16): device-scope atomics + agent
// fences. Safe because all 512 blocks are co-resident by construction:
// 0 LDS, __launch_bounds__(256,2) => 2 blocks/CU x 256 CUs. Counters are
// zeroed by a hipMemsetAsync enqueued before the kernel each graph replay.
// (cooperative launch is NOT capture-safe in this harness -- round-2 lesson.)
// ---------------------------------------------------------------------------
static __device__ inline void grid_barrier(unsigned* __restrict__ ctr)
{
    __syncthreads();
    if (threadIdx.x == 0) {
        __threadfence();   // release: drain our global writes to coherent point
        __hip_atomic_fetch_add(ctr, 1u, __ATOMIC_ACQ_REL, __HIP_MEMORY_SCOPE_AGENT);
        while (__hip_atomic_load(ctr, __ATOMIC_ACQUIRE, __HIP_MEMORY_SCOPE_AGENT) < (unsigned)NBLOCKS)
            __builtin_amdgcn_s_sleep(2);
        __threadfence();   // acquire: invalidate stale L1/L2 before phase reads
    }
    __syncthreads();
}

// ---------------------------------------------------------------------------
// Single fused kernel, 512 blocks x 256 threads, 4 phases:
//   phase 0 (blocks 0..255): weight prep (pack win; fuse wt@wout)
//   phase 1 (all 512):       MFMA QKV projection -> Qpk/Kpk/Vt
//   phase 2 (all 512):       MFMA flash attention -> Opk
//   phase 3 (all 512):       MFMA output projection -> out
// Phase arithmetic is byte-identical to the round-1 verified 4-kernel
// version (165.6 us). Fusion removes 3 inter-kernel gaps + wave ramps.
// ---------------------------------------------------------------------------
__global__ __launch_bounds__(256, 2) void fused_mab_kernel(
    const float* __restrict__ x_re,   const float* __restrict__ x_im,
    const float* __restrict__ win_re, const float* __restrict__ win_im,
    const float* __restrict__ bin_re, const float* __restrict__ bin_im,
    const float* __restrict__ wout_re,const float* __restrict__ wout_im,
    const float* __restrict__ bout_re,const float* __restrict__ bout_im,
    const float* __restrict__ wt_re,  const float* __restrict__ wt_im,
    const float* __restrict__ bt_re,  const float* __restrict__ bt_im,
    short* __restrict__ Qpk,  short* __restrict__ Kpk,
    short* __restrict__ Vtre, short* __restrict__ Vtim,
    short* __restrict__ Opk,
    short* __restrict__ Wp_re,  short* __restrict__ Wp_im,
    short* __restrict__ Wfp_re, short* __restrict__ Wfp_im,
    float* __restrict__ bf_re,  float* __restrict__ bf_im,
    unsigned* __restrict__ bars,
    float* __restrict__ out)
{
    int bid  = blockIdx.x;             // [0, 512)
    int tid  = threadIdx.x;
    int wave = tid >> 6, lane = tid & 63;
    int col  = lane & 15, quad = lane >> 4;

    // ---------------- phase 0: weight prep ----------------
    if (bid < E3*E/256) {
        // pack win into bf16 K=256 complex-packed layout
        int idx = bid * 256 + tid;     // [0, 384*128)
        int j = idx >> 7, e = idx & 127;
        float wr = win_re[idx], wi = win_im[idx];
        Wp_re[j*256 + e]       = bf16s(wr);
        Wp_re[j*256 + 128 + e] = bf16s(-wi);
        Wp_im[j*256 + e]       = bf16s(wi);
        Wp_im[j*256 + 128 + e] = bf16s(wr);
    } else if (bid < E3*E/256 + E*E/256) {
        // fuse output linears: wf = wt @ wout, bf = wt @ bout + bt (complex)
        int idx = (bid - E3*E/256) * 256 + tid;   // [0, E*E)
        int j = idx >> 7, e = idx & 127;
        float ar = 0.f, ai = 0.f;
        for (int m = 0; m < E; ++m) {
            float tr = wt_re[j*E+m], ti = wt_im[j*E+m];
            float pr = wout_re[m*E+e], pi = wout_im[m*E+e];
            ar += tr*pr - ti*pi;
            ai += tr*pi + ti*pr;
        }
        Wfp_re[j*256 + e]       = bf16s(ar);
        Wfp_re[j*256 + 128 + e] = bf16s(-ai);
        Wfp_im[j*256 + e]       = bf16s(ai);
        Wfp_im[j*256 + 128 + e] = bf16s(ar);
        if (idx < E) {
            float br = bt_re[idx], bi = bt_im[idx];
            for (int m = 0; m < E; ++m) {
                float tr = wt_re[idx*E+m], ti = wt_im[idx*E+m];
                br += tr*bout_re[m] - ti*bout_im[m];
                bi += tr*bout_im[m] + ti*bout_re[m];
            }
            bf_re[idx] = br; bf_im[idx] = bi;
        }
    }

    grid_barrier(&bars[0]);

    // ---------------- phase 1: QKV projection ----------------
    {
        int ttile = bid;               // [0, 512)
        int b  = ttile >> 6;
        int tb = (ttile & 63) * 16 + col;

        // X fragments for 8 k-tiles, loaded once, reused for re+im halves
        short8 xf[8];
        #pragma unroll
        for (int kt = 0; kt < 8; ++kt) {
            const float* xs = (kt < 4) ? x_re : x_im;
            const float* p = &xs[((long)(b*E + (kt & 3)*32 + quad*8))*T + tb];
            float v0 = p[0], v1 = p[(long)T], v2 = p[2L*T], v3 = p[3L*T];
            float v4 = p[4L*T], v5 = p[5L*T], v6 = p[6L*T], v7 = p[7L*T];
            __hip_bfloat162* xp = (__hip_bfloat162*)&xf[kt];
            xp[0] = pk2(v0, v1); xp[1] = pk2(v2, v3);
            xp[2] = pk2(v4, v5); xp[3] = pk2(v6, v7);
        }

        const f32x4 zero = {0.f,0.f,0.f,0.f};

        #pragma unroll
        for (int half = 0; half < 2; ++half) {
            const short* Wsel = half ? Wp_im : Wp_re;
            const float* bias = half ? bin_im : bin_re;

            for (int ni = 0; ni < 6; ++ni) {
                int jt = wave * 6 + ni;            // [0,24): which*8 + h
                const short* wrow = &Wsel[(jt*16 + col)*256 + quad*8];
                f32x4 acc = zero;
                #pragma unroll
                for (int kt = 0; kt < 8; ++kt) {
                    short8 af = *(const short8*)(wrow + kt*32);
                    acc = __builtin_amdgcn_mfma_f32_16x16x32_bf16(af, xf[kt], acc, 0, 0, 0);
                }
                int which = jt >> 3;               // 0 q, 1 k, 2 v
                int h = jt & 7;
                float scale = (which == 0) ? QSCALE : 1.0f;
                f32x4 res;
                #pragma unroll
                for (int r = 0; r < 4; ++r) {
                    int jg = which*128 + h*16 + quad*4 + r;
                    res[r] = (acc[r] + bias[jg]) * scale;
                }
                long bh = b*H + h;
                if (which == 2) {
                    // V transposed + pi-interleaved: Vt[bh][dh][blk*32 + pos]
                    short* vt = half ? Vtim : Vtre;
                    int tloc = tb & 31, tblk = tb & ~31;
                    int u  = tloc & 15;
                    int kk = (u >> 2)*8 + (u & 3) + ((tloc >= 16) ? 4 : 0);
                    #pragma unroll
                    for (int r = 0; r < 4; ++r)
                        vt[(bh*DH + quad*4 + r)*T + tblk + kk] = bf16s(res[r]);
                } else {
                    short* qk = (which == 0) ? Qpk : Kpk;
                    short4s pk;
                    __hip_bfloat162* pp = (__hip_bfloat162*)&pk;
                    pp[0] = pk2(res[0], res[1]);
                    pp[1] = pk2(res[2], res[3]);
                    *(short4s*)&qk[(bh*T + tb)*32 + half*16 + quad*4] = pk;
                }
            }
        }
    }

    grid_barrier(&bars[16]);

    // ---------------- phase 2: flash attention ----------------
    {
        int bh   = bid & 63;
        int q0   = (bid >> 6) * 128;
        long kq_base = (long)bh * T * 32;
        int qbase = q0 + wave * 32;

        short8 qfA = *(const short8*)&Qpk[kq_base + (long)(qbase + col)*32 + quad*8];
        short8 qfB = *(const short8*)&Qpk[kq_base + (long)(qbase + 16 + col)*32 + quad*8];

        const short* kp  = &Kpk[kq_base + col*32 + quad*8];
        const short* vrp = &Vtre[(long)bh*DH*T + (long)col*T + quad*8];
        const short* vip = &Vtim[(long)bh*DH*T + (long)col*T + quad*8];

        short8 ones;
        #pragma unroll
        for (int i = 0; i < 8; ++i) ones[i] = (short)0x3F80;   // bf16 1.0

        f32x4 oAr = {0,0,0,0}, oAi = {0,0,0,0}, lA = {0,0,0,0};
        f32x4 oBr = {0,0,0,0}, oBi = {0,0,0,0}, lB = {0,0,0,0};
        const f32x4 zero = {0.f,0.f,0.f,0.f};

        auto STEP = [&](short8 kf0, short8 kf1, short8 vr, short8 vi) {
            __builtin_amdgcn_s_setprio(1);
            f32x4 sA0 = __builtin_amdgcn_mfma_f32_16x16x32_bf16(kf0, qfA, zero, 0, 0, 0);
            f32x4 sA1 = __builtin_amdgcn_mfma_f32_16x16x32_bf16(kf1, qfA, zero, 0, 0, 0);
            f32x4 sB0 = __builtin_amdgcn_mfma_f32_16x16x32_bf16(kf0, qfB, zero, 0, 0, 0);
            f32x4 sB1 = __builtin_amdgcn_mfma_f32_16x16x32_bf16(kf1, qfB, zero, 0, 0, 0);
            __builtin_amdgcn_s_setprio(0);

            short8 pfA, pfB;
            {
                __hip_bfloat162* pa = (__hip_bfloat162*)&pfA;
                pa[0] = pk2(fexp2(sA0[0]), fexp2(sA0[1]));
                pa[1] = pk2(fexp2(sA0[2]), fexp2(sA0[3]));
                pa[2] = pk2(fexp2(sA1[0]), fexp2(sA1[1]));
                pa[3] = pk2(fexp2(sA1[2]), fexp2(sA1[3]));
                __hip_bfloat162* pb = (__hip_bfloat162*)&pfB;
                pb[0] = pk2(fexp2(sB0[0]), fexp2(sB0[1]));
                pb[1] = pk2(fexp2(sB0[2]), fexp2(sB0[3]));
                pb[2] = pk2(fexp2(sB1[0]), fexp2(sB1[1]));
                pb[3] = pk2(fexp2(sB1[2]), fexp2(sB1[3]));
            }

            __builtin_amdgcn_s_setprio(1);
            oAr = __builtin_amdgcn_mfma_f32_16x16x32_bf16(vr, pfA, oAr, 0, 0, 0);
            oAi = __builtin_amdgcn_mfma_f32_16x16x32_bf16(vi, pfA, oAi, 0, 0, 0);
            lA  = __builtin_amdgcn_mfma_f32_16x16x32_bf16(ones, pfA, lA, 0, 0, 0);
            oBr = __builtin_amdgcn_mfma_f32_16x16x32_bf16(vr, pfB, oBr, 0, 0, 0);
            oBi = __builtin_amdgcn_mfma_f32_16x16x32_bf16(vi, pfB, oBi, 0, 0, 0);
            lB  = __builtin_amdgcn_mfma_f32_16x16x32_bf16(ones, pfB, lB, 0, 0, 0);
            __builtin_amdgcn_s_setprio(0);
        };

        // prologue: tiles 0 and 1 in flight (distance-2 pipeline)
        short8 k0A = *(const short8*)kp;
        short8 k1A = *(const short8*)(kp + 512);
        short8 vrA = *(const short8*)vrp;
        short8 viA = *(const short8*)vip;
        short8 k0B = *(const short8*)(kp + 1024);
        short8 k1B = *(const short8*)(kp + 1536);
        short8 vrB = *(const short8*)(vrp + 32);
        short8 viB = *(const short8*)(vip + 32);
        kp += 2048; vrp += 64; vip += 64;

        for (int i = 0; i < 32; i += 2) {
            // prefetch tile i+2 (tail over-reads land in adjacent ws, unused)
            short8 k0n = *(const short8*)kp;
            short8 k1n = *(const short8*)(kp + 512);
            short8 vrn = *(const short8*)vrp;
            short8 vin = *(const short8*)vip;
            kp += 1024; vrp += 32; vip += 32;

            STEP(k0A, k1A, vrA, viA);                    // tile i
            k0A = k0n; k1A = k1n; vrA = vrn; viA = vin;

            // prefetch tile i+3
            k0n = *(const short8*)kp;
            k1n = *(const short8*)(kp + 512);
            vrn = *(const short8*)vrp;
            vin = *(const short8*)vip;
            kp += 1024; vrp += 32; vip += 32;

            STEP(k0B, k1B, vrB, viB);                    // tile i+1
            k0B = k0n; k1B = k1n; vrB = vrn; viB = vin;
        }

        int b = bh >> 3, h = bh & 7;
        float invA = 1.0f / lA[0];
        float invB = 1.0f / lB[0];

        long orowA = ((long)(b*T + qbase + col))*256 + h*16 + quad*4;
        {
            short4s pr, pi_;
            __hip_bfloat162* a = (__hip_bfloat162*)&pr;
            a[0] = pk2(oAr[0]*invA, oAr[1]*invA);
            a[1] = pk2(oAr[2]*invA, oAr[3]*invA);
            __hip_bfloat162* c = (__hip_bfloat162*)&pi_;
            c[0] = pk2(oAi[0]*invA, oAi[1]*invA);
            c[1] = pk2(oAi[2]*invA, oAi[3]*invA);
            *(short4s*)&Opk[orowA]       = pr;
            *(short4s*)&Opk[orowA + 128] = pi_;
        }
        long orowB = orowA + 16L*256;
        {
            short4s pr, pi_;
            __hip_bfloat162* a = (__hip_bfloat162*)&pr;
            a[0] = pk2(oBr[0]*invB, oBr[1]*invB);
            a[1] = pk2(oBr[2]*invB, oBr[3]*invB);
            __hip_bfloat162* c = (__hip_bfloat162*)&pi_;
            c[0] = pk2(oBi[0]*invB, oBi[1]*invB);
            c[1] = pk2(oBi[2]*invB, oBi[3]*invB);
            *(short4s*)&Opk[orowB]       = pr;
            *(short4s*)&Opk[orowB + 128] = pi_;
        }
    }

    grid_barrier(&bars[32]);

    // ---------------- phase 3: output projection ----------------
    {
        int ttile = bid;               // [0,512)
        int b  = ttile >> 6;
        int tb = (ttile & 63) * 16 + col;
        long trow = (long)b*T + tb;

        short8 xf[8];
        #pragma unroll
        for (int kt = 0; kt < 8; ++kt)
            xf[kt] = *(const short8*)&Opk[trow*256 + kt*32 + quad*8];

        const f32x4 zero = {0.f,0.f,0.f,0.f};
        #pragma unroll
        for (int ni = 0; ni < 4; ++ni) {
            int nt = wave * 4 + ni;            // [0,16)
            int is_im = nt >= 8;
            int jt = is_im ? nt - 8 : nt;      // [0,8)
            const short* Wsel = is_im ? Wfp_im : Wfp_re;
            const short* wrow = &Wsel[(jt*16 + col)*256 + quad*8];
            f32x4 acc = zero;
            #pragma unroll
            for (int kt = 0; kt < 8; ++kt) {
                short8 af = *(const short8*)(wrow + kt*32);
                acc = __builtin_amdgcn_mfma_f32_16x16x32_bf16(af, xf[kt], acc, 0, 0, 0);
            }
            const float* bias = is_im ? bf_im : bf_re;
            long part = is_im ? (long)B*E*T : 0;
            #pragma unroll
            for (int r = 0; r < 4; ++r) {
                int j = jt*16 + quad*4 + r;
                out[part + ((long)(b*E + j))*T + tb] = acc[r] + bias[j];
            }
        }
    }
}

// ---------------------------------------------------------------------------
extern "C" void kernel_launch(void* const* d_in, const int* in_sizes, int n_in,
                              void* d_out, int out_size, void* d_ws, size_t ws_size,
                              hipStream_t stream)
{
    const float* x_re    = (const float*)d_in[0];
    const float* x_im    = (const float*)d_in[1];
    const float* win_re  = (const float*)d_in[2];
    const float* win_im  = (const float*)d_in[3];
    const float* bin_re  = (const float*)d_in[4];
    const float* bin_im  = (const float*)d_in[5];
    const float* wout_re = (const float*)d_in[6];
    const float* wout_im = (const float*)d_in[7];
    const float* bout_re = (const float*)d_in[8];
    const float* bout_im = (const float*)d_in[9];
    const float* wt_re   = (const float*)d_in[10];
    const float* wt_im   = (const float*)d_in[11];
    const float* bt_re   = (const float*)d_in[12];
    const float* bt_im   = (const float*)d_in[13];
    float* out = (float*)d_out;

    // workspace layout (shorts/floats)
    short* Qpk  = (short*)d_ws;                       // 64*1024*32 = 2M shorts
    short* Kpk  = Qpk + (long)B*H*T*32;
    short* Vtre = Kpk + (long)B*H*T*32;               // 64*16*1024 = 1M shorts
    short* Vtim = Vtre + (long)B*H*DH*T;
    short* Opk  = Vtim + (long)B*H*DH*T;              // 8*1024*256 = 2M shorts
    short* Wp_re  = Opk + (long)B*T*256;
    short* Wp_im  = Wp_re + E3*256;
    short* Wfp_re = Wp_im + E3*256;
    short* Wfp_im = Wfp_re + E*256;
    float* bf_re  = (float*)(Wfp_im + E*256);
    float* bf_im  = bf_re + E;

    // barrier counters: far past used region (~16.5 MiB), 32 MiB offset
    unsigned* bars = (unsigned*)((char*)d_ws + (32u << 20));

    // re-arm barriers every replay (enqueued before the kernel, capture-safe)
    hipMemsetAsync(bars, 0, 256, stream);

    fused_mab_kernel<<<dim3(NBLOCKS), dim3(256), 0, stream>>>(
        x_re, x_im, win_re, win_im, bin_re, bin_im,
        wout_re, wout_im, bout_re, bout_im,
        wt_re, wt_im, bt_re, bt_im,
        Qpk, Kpk, Vtre, Vtim, Opk,
        Wp_re, Wp_im, Wfp_re, Wfp_im, bf_re, bf_im,
        bars, out);
}

// Round 4
// 267.653 us; speedup vs baseline: 1.5720x; 1.5720x over previous
//
#include <hip/hip_runtime.h>
#include <hip/hip_bf16.h>

#define B 8
#define T 1024
#define E 128
#define H 8
#define DH 16
#define E3 384

#define NBLOCKS 512

typedef __attribute__((ext_vector_type(8))) short short8;
typedef __attribute__((ext_vector_type(4))) short short4s;
typedef __attribute__((ext_vector_type(4))) float f32x4;

// fp32 -> bf16 (round-to-nearest-even), bit pattern in a short
static __device__ inline short bf16s(float x) {
    union { float f; unsigned u; } v; v.f = x;
    unsigned r = v.u + 0x7fffu + ((v.u >> 16) & 1u);
    return (short)(r >> 16);
}

// exp2 via the HW transcendental (1 inst)
#if __has_builtin(__builtin_amdgcn_exp2f)
static __device__ inline float fexp2(float x) { return __builtin_amdgcn_exp2f(x); }
#else
static __device__ inline float fexp2(float x) { return __builtin_exp2f(x); }
#endif

// pack two fp32 into bf16x2 via v_cvt_pk_bf16_f32
static __device__ inline __hip_bfloat162 pk2(float a, float b) {
    float2 t; t.x = a; t.y = b;
    return __float22bfloat162_rn(t);
}

#define QSCALE 0.36067376022224085f   /* 0.25 * log2(e) */

// ---------------------------------------------------------------------------
// Hand-rolled grid barrier. Round-3 lesson: an agent-scope ACQUIRE load in
// the spin loop emits buffer_inv sc1 EVERY poll -> continuous per-XCD L2
// invalidate storm (354 us kernel, 148 GB/s). Fix: RELAXED poll (no cache
// maintenance; still observes MALL-level atomic adds), then exactly ONE
// acquire fence (__threadfence, acq_rel agent) after the loop exits.
// Co-residency: 0 LDS, __launch_bounds__(256,2) => 2 blocks/CU x 256 CU
// = 512 blocks all resident; counters re-armed by hipMemsetAsync pre-kernel.
// ---------------------------------------------------------------------------
static __device__ inline void grid_barrier(unsigned* __restrict__ ctr)
{
    __syncthreads();
    if (threadIdx.x == 0) {
        // RELEASE add: one buffer_wbl2 (drain our writes), then the atomic.
        __hip_atomic_fetch_add(ctr, 1u, __ATOMIC_RELEASE, __HIP_MEMORY_SCOPE_AGENT);
        // RELAXED poll: no buffer_inv per iteration.
        while (__hip_atomic_load(ctr, __ATOMIC_RELAXED, __HIP_MEMORY_SCOPE_AGENT) < (unsigned)NBLOCKS)
            __builtin_amdgcn_s_sleep(8);
        __threadfence();   // ONE acquire: invalidate stale L1/L2 before reads
    }
    __syncthreads();
}

// ---------------------------------------------------------------------------
// Single fused kernel, 512 blocks x 256 threads, 4 phases:
//   phase 0 (blocks 0..255): weight prep (pack win; fuse wt@wout)
//   phase 1 (all 512):       MFMA QKV projection -> Qpk/Kpk/Vt
//   phase 2 (all 512):       MFMA flash attention -> Opk
//   phase 3 (all 512):       MFMA output projection -> out
// Phase arithmetic is byte-identical to the round-1 verified 4-kernel
// version (165.6 us). Fusion removes 3 inter-kernel gaps + wave ramps.
// ---------------------------------------------------------------------------
__global__ __launch_bounds__(256, 2) void fused_mab_kernel(
    const float* __restrict__ x_re,   const float* __restrict__ x_im,
    const float* __restrict__ win_re, const float* __restrict__ win_im,
    const float* __restrict__ bin_re, const float* __restrict__ bin_im,
    const float* __restrict__ wout_re,const float* __restrict__ wout_im,
    const float* __restrict__ bout_re,const float* __restrict__ bout_im,
    const float* __restrict__ wt_re,  const float* __restrict__ wt_im,
    const float* __restrict__ bt_re,  const float* __restrict__ bt_im,
    short* __restrict__ Qpk,  short* __restrict__ Kpk,
    short* __restrict__ Vtre, short* __restrict__ Vtim,
    short* __restrict__ Opk,
    short* __restrict__ Wp_re,  short* __restrict__ Wp_im,
    short* __restrict__ Wfp_re, short* __restrict__ Wfp_im,
    float* __restrict__ bf_re,  float* __restrict__ bf_im,
    unsigned* __restrict__ bars,
    float* __restrict__ out)
{
    int bid  = blockIdx.x;             // [0, 512)
    int tid  = threadIdx.x;
    int wave = tid >> 6, lane = tid & 63;
    int col  = lane & 15, quad = lane >> 4;

    // ---------------- phase 0: weight prep ----------------
    if (bid < E3*E/256) {
        // pack win into bf16 K=256 complex-packed layout
        int idx = bid * 256 + tid;     // [0, 384*128)
        int j = idx >> 7, e = idx & 127;
        float wr = win_re[idx], wi = win_im[idx];
        Wp_re[j*256 + e]       = bf16s(wr);
        Wp_re[j*256 + 128 + e] = bf16s(-wi);
        Wp_im[j*256 + e]       = bf16s(wi);
        Wp_im[j*256 + 128 + e] = bf16s(wr);
    } else if (bid < E3*E/256 + E*E/256) {
        // fuse output linears: wf = wt @ wout, bf = wt @ bout + bt (complex)
        int idx = (bid - E3*E/256) * 256 + tid;   // [0, E*E)
        int j = idx >> 7, e = idx & 127;
        float ar = 0.f, ai = 0.f;
        for (int m = 0; m < E; ++m) {
            float tr = wt_re[j*E+m], ti = wt_im[j*E+m];
            float pr = wout_re[m*E+e], pi = wout_im[m*E+e];
            ar += tr*pr - ti*pi;
            ai += tr*pi + ti*pr;
        }
        Wfp_re[j*256 + e]       = bf16s(ar);
        Wfp_re[j*256 + 128 + e] = bf16s(-ai);
        Wfp_im[j*256 + e]       = bf16s(ai);
        Wfp_im[j*256 + 128 + e] = bf16s(ar);
        if (idx < E) {
            float br = bt_re[idx], bi = bt_im[idx];
            for (int m = 0; m < E; ++m) {
                float tr = wt_re[idx*E+m], ti = wt_im[idx*E+m];
                br += tr*bout_re[m] - ti*bout_im[m];
                bi += tr*bout_im[m] + ti*bout_re[m];
            }
            bf_re[idx] = br; bf_im[idx] = bi;
        }
    }

    grid_barrier(&bars[0]);

    // ---------------- phase 1: QKV projection ----------------
    {
        int ttile = bid;               // [0, 512)
        int b  = ttile >> 6;
        int tb = (ttile & 63) * 16 + col;

        // X fragments for 8 k-tiles, loaded once, reused for re+im halves
        short8 xf[8];
        #pragma unroll
        for (int kt = 0; kt < 8; ++kt) {
            const float* xs = (kt < 4) ? x_re : x_im;
            const float* p = &xs[((long)(b*E + (kt & 3)*32 + quad*8))*T + tb];
            float v0 = p[0], v1 = p[(long)T], v2 = p[2L*T], v3 = p[3L*T];
            float v4 = p[4L*T], v5 = p[5L*T], v6 = p[6L*T], v7 = p[7L*T];
            __hip_bfloat162* xp = (__hip_bfloat162*)&xf[kt];
            xp[0] = pk2(v0, v1); xp[1] = pk2(v2, v3);
            xp[2] = pk2(v4, v5); xp[3] = pk2(v6, v7);
        }

        const f32x4 zero = {0.f,0.f,0.f,0.f};

        #pragma unroll
        for (int half = 0; half < 2; ++half) {
            const short* Wsel = half ? Wp_im : Wp_re;
            const float* bias = half ? bin_im : bin_re;

            for (int ni = 0; ni < 6; ++ni) {
                int jt = wave * 6 + ni;            // [0,24): which*8 + h
                const short* wrow = &Wsel[(jt*16 + col)*256 + quad*8];
                f32x4 acc = zero;
                #pragma unroll
                for (int kt = 0; kt < 8; ++kt) {
                    short8 af = *(const short8*)(wrow + kt*32);
                    acc = __builtin_amdgcn_mfma_f32_16x16x32_bf16(af, xf[kt], acc, 0, 0, 0);
                }
                int which = jt >> 3;               // 0 q, 1 k, 2 v
                int h = jt & 7;
                float scale = (which == 0) ? QSCALE : 1.0f;
                f32x4 res;
                #pragma unroll
                for (int r = 0; r < 4; ++r) {
                    int jg = which*128 + h*16 + quad*4 + r;
                    res[r] = (acc[r] + bias[jg]) * scale;
                }
                long bh = b*H + h;
                if (which == 2) {
                    // V transposed + pi-interleaved: Vt[bh][dh][blk*32 + pos]
                    short* vt = half ? Vtim : Vtre;
                    int tloc = tb & 31, tblk = tb & ~31;
                    int u  = tloc & 15;
                    int kk = (u >> 2)*8 + (u & 3) + ((tloc >= 16) ? 4 : 0);
                    #pragma unroll
                    for (int r = 0; r < 4; ++r)
                        vt[(bh*DH + quad*4 + r)*T + tblk + kk] = bf16s(res[r]);
                } else {
                    short* qk = (which == 0) ? Qpk : Kpk;
                    short4s pk;
                    __hip_bfloat162* pp = (__hip_bfloat162*)&pk;
                    pp[0] = pk2(res[0], res[1]);
                    pp[1] = pk2(res[2], res[3]);
                    *(short4s*)&qk[(bh*T + tb)*32 + half*16 + quad*4] = pk;
                }
            }
        }
    }

    grid_barrier(&bars[16]);

    // ---------------- phase 2: flash attention ----------------
    {
        int bh   = bid & 63;
        int q0   = (bid >> 6) * 128;
        long kq_base = (long)bh * T * 32;
        int qbase = q0 + wave * 32;

        short8 qfA = *(const short8*)&Qpk[kq_base + (long)(qbase + col)*32 + quad*8];
        short8 qfB = *(const short8*)&Qpk[kq_base + (long)(qbase + 16 + col)*32 + quad*8];

        const short* kp  = &Kpk[kq_base + col*32 + quad*8];
        const short* vrp = &Vtre[(long)bh*DH*T + (long)col*T + quad*8];
        const short* vip = &Vtim[(long)bh*DH*T + (long)col*T + quad*8];

        short8 ones;
        #pragma unroll
        for (int i = 0; i < 8; ++i) ones[i] = (short)0x3F80;   // bf16 1.0

        f32x4 oAr = {0,0,0,0}, oAi = {0,0,0,0}, lA = {0,0,0,0};
        f32x4 oBr = {0,0,0,0}, oBi = {0,0,0,0}, lB = {0,0,0,0};
        const f32x4 zero = {0.f,0.f,0.f,0.f};

        auto STEP = [&](short8 kf0, short8 kf1, short8 vr, short8 vi) {
            __builtin_amdgcn_s_setprio(1);
            f32x4 sA0 = __builtin_amdgcn_mfma_f32_16x16x32_bf16(kf0, qfA, zero, 0, 0, 0);
            f32x4 sA1 = __builtin_amdgcn_mfma_f32_16x16x32_bf16(kf1, qfA, zero, 0, 0, 0);
            f32x4 sB0 = __builtin_amdgcn_mfma_f32_16x16x32_bf16(kf0, qfB, zero, 0, 0, 0);
            f32x4 sB1 = __builtin_amdgcn_mfma_f32_16x16x32_bf16(kf1, qfB, zero, 0, 0, 0);
            __builtin_amdgcn_s_setprio(0);

            short8 pfA, pfB;
            {
                __hip_bfloat162* pa = (__hip_bfloat162*)&pfA;
                pa[0] = pk2(fexp2(sA0[0]), fexp2(sA0[1]));
                pa[1] = pk2(fexp2(sA0[2]), fexp2(sA0[3]));
                pa[2] = pk2(fexp2(sA1[0]), fexp2(sA1[1]));
                pa[3] = pk2(fexp2(sA1[2]), fexp2(sA1[3]));
                __hip_bfloat162* pb = (__hip_bfloat162*)&pfB;
                pb[0] = pk2(fexp2(sB0[0]), fexp2(sB0[1]));
                pb[1] = pk2(fexp2(sB0[2]), fexp2(sB0[3]));
                pb[2] = pk2(fexp2(sB1[0]), fexp2(sB1[1]));
                pb[3] = pk2(fexp2(sB1[2]), fexp2(sB1[3]));
            }

            __builtin_amdgcn_s_setprio(1);
            oAr = __builtin_amdgcn_mfma_f32_16x16x32_bf16(vr, pfA, oAr, 0, 0, 0);
            oAi = __builtin_amdgcn_mfma_f32_16x16x32_bf16(vi, pfA, oAi, 0, 0, 0);
            lA  = __builtin_amdgcn_mfma_f32_16x16x32_bf16(ones, pfA, lA, 0, 0, 0);
            oBr = __builtin_amdgcn_mfma_f32_16x16x32_bf16(vr, pfB, oBr, 0, 0, 0);
            oBi = __builtin_amdgcn_mfma_f32_16x16x32_bf16(vi, pfB, oBi, 0, 0, 0);
            lB  = __builtin_amdgcn_mfma_f32_16x16x32_bf16(ones, pfB, lB, 0, 0, 0);
            __builtin_amdgcn_s_setprio(0);
        };

        // prologue: tiles 0 and 1 in flight (distance-2 pipeline)
        short8 k0A = *(const short8*)kp;
        short8 k1A = *(const short8*)(kp + 512);
        short8 vrA = *(const short8*)vrp;
        short8 viA = *(const short8*)vip;
        short8 k0B = *(const short8*)(kp + 1024);
        short8 k1B = *(const short8*)(kp + 1536);
        short8 vrB = *(const short8*)(vrp + 32);
        short8 viB = *(const short8*)(vip + 32);
        kp += 2048; vrp += 64; vip += 64;

        for (int i = 0; i < 32; i += 2) {
            // prefetch tile i+2 (tail over-reads land in adjacent ws, unused)
            short8 k0n = *(const short8*)kp;
            short8 k1n = *(const short8*)(kp + 512);
            short8 vrn = *(const short8*)vrp;
            short8 vin = *(const short8*)vip;
            kp += 1024; vrp += 32; vip += 32;

            STEP(k0A, k1A, vrA, viA);                    // tile i
            k0A = k0n; k1A = k1n; vrA = vrn; viA = vin;

            // prefetch tile i+3
            k0n = *(const short8*)kp;
            k1n = *(const short8*)(kp + 512);
            vrn = *(const short8*)vrp;
            vin = *(const short8*)vip;
            kp += 1024; vrp += 32; vip += 32;

            STEP(k0B, k1B, vrB, viB);                    // tile i+1
            k0B = k0n; k1B = k1n; vrB = vrn; viB = vin;
        }

        int b = bh >> 3, h = bh & 7;
        float invA = 1.0f / lA[0];
        float invB = 1.0f / lB[0];

        long orowA = ((long)(b*T + qbase + col))*256 + h*16 + quad*4;
        {
            short4s pr, pi_;
            __hip_bfloat162* a = (__hip_bfloat162*)&pr;
            a[0] = pk2(oAr[0]*invA, oAr[1]*invA);
            a[1] = pk2(oAr[2]*invA, oAr[3]*invA);
            __hip_bfloat162* c = (__hip_bfloat162*)&pi_;
            c[0] = pk2(oAi[0]*invA, oAi[1]*invA);
            c[1] = pk2(oAi[2]*invA, oAi[3]*invA);
            *(short4s*)&Opk[orowA]       = pr;
            *(short4s*)&Opk[orowA + 128] = pi_;
        }
        long orowB = orowA + 16L*256;
        {
            short4s pr, pi_;
            __hip_bfloat162* a = (__hip_bfloat162*)&pr;
            a[0] = pk2(oBr[0]*invB, oBr[1]*invB);
            a[1] = pk2(oBr[2]*invB, oBr[3]*invB);
            __hip_bfloat162* c = (__hip_bfloat162*)&pi_;
            c[0] = pk2(oBi[0]*invB, oBi[1]*invB);
            c[1] = pk2(oBi[2]*invB, oBi[3]*invB);
            *(short4s*)&Opk[orowB]       = pr;
            *(short4s*)&Opk[orowB + 128] = pi_;
        }
    }

    grid_barrier(&bars[32]);

    // ---------------- phase 3: output projection ----------------
    {
        int ttile = bid;               // [0,512)
        int b  = ttile >> 6;
        int tb = (ttile & 63) * 16 + col;
        long trow = (long)b*T + tb;

        short8 xf[8];
        #pragma unroll
        for (int kt = 0; kt < 8; ++kt)
            xf[kt] = *(const short8*)&Opk[trow*256 + kt*32 + quad*8];

        const f32x4 zero = {0.f,0.f,0.f,0.f};
        #pragma unroll
        for (int ni = 0; ni < 4; ++ni) {
            int nt = wave * 4 + ni;            // [0,16)
            int is_im = nt >= 8;
            int jt = is_im ? nt - 8 : nt;      // [0,8)
            const short* Wsel = is_im ? Wfp_im : Wfp_re;
            const short* wrow = &Wsel[(jt*16 + col)*256 + quad*8];
            f32x4 acc = zero;
            #pragma unroll
            for (int kt = 0; kt < 8; ++kt) {
                short8 af = *(const short8*)(wrow + kt*32);
                acc = __builtin_amdgcn_mfma_f32_16x16x32_bf16(af, xf[kt], acc, 0, 0, 0);
            }
            const float* bias = is_im ? bf_im : bf_re;
            long part = is_im ? (long)B*E*T : 0;
            #pragma unroll
            for (int r = 0; r < 4; ++r) {
                int j = jt*16 + quad*4 + r;
                out[part + ((long)(b*E + j))*T + tb] = acc[r] + bias[j];
            }
        }
    }
}

// ---------------------------------------------------------------------------
extern "C" void kernel_launch(void* const* d_in, const int* in_sizes, int n_in,
                              void* d_out, int out_size, void* d_ws, size_t ws_size,
                              hipStream_t stream)
{
    const float* x_re    = (const float*)d_in[0];
    const float* x_im    = (const float*)d_in[1];
    const float* win_re  = (const float*)d_in[2];
    const float* win_im  = (const float*)d_in[3];
    const float* bin_re  = (const float*)d_in[4];
    const float* bin_im  = (const float*)d_in[5];
    const float* wout_re = (const float*)d_in[6];
    const float* wout_im = (const float*)d_in[7];
    const float* bout_re = (const float*)d_in[8];
    const float* bout_im = (const float*)d_in[9];
    const float* wt_re   = (const float*)d_in[10];
    const float* wt_im   = (const float*)d_in[11];
    const float* bt_re   = (const float*)d_in[12];
    const float* bt_im   = (const float*)d_in[13];
    float* out = (float*)d_out;

    // workspace layout (shorts/floats)
    short* Qpk  = (short*)d_ws;                       // 64*1024*32 = 2M shorts
    short* Kpk  = Qpk + (long)B*H*T*32;
    short* Vtre = Kpk + (long)B*H*T*32;               // 64*16*1024 = 1M shorts
    short* Vtim = Vtre + (long)B*H*DH*T;
    short* Opk  = Vtim + (long)B*H*DH*T;              // 8*1024*256 = 2M shorts
    short* Wp_re  = Opk + (long)B*T*256;
    short* Wp_im  = Wp_re + E3*256;
    short* Wfp_re = Wp_im + E3*256;
    short* Wfp_im = Wfp_re + E*256;
    float* bf_re  = (float*)(Wfp_im + E*256);
    float* bf_im  = bf_re + E;

    // barrier counters: far past used region (~16.5 MiB), 32 MiB offset
    unsigned* bars = (unsigned*)((char*)d_ws + (32u << 20));

    // re-arm barriers every replay (enqueued before the kernel, capture-safe)
    hipMemsetAsync(bars, 0, 256, stream);

    fused_mab_kernel<<<dim3(NBLOCKS), dim3(256), 0, stream>>>(
        x_re, x_im, win_re, win_im, bin_re, bin_im,
        wout_re, wout_im, bout_re, bout_im,
        wt_re, wt_im, bt_re, bt_im,
        Qpk, Kpk, Vtre, Vtim, Opk,
        Wp_re, Wp_im, Wfp_re, Wfp_im, bf_re, bf_im,
        bars, out);
}

// Round 5
// 183.762 us; speedup vs baseline: 2.2897x; 1.4565x over previous
//
#include <hip/hip_runtime.h>
#include <hip/hip_bf16.h>

#define B 8
#define T 1024
#define E 128
#define H 8
#define DH 16
#define E3 384

typedef __attribute__((ext_vector_type(8))) short short8;
typedef __attribute__((ext_vector_type(4))) short short4s;
typedef __attribute__((ext_vector_type(4))) float f32x4;

// fp32 -> bf16 (round-to-nearest-even), bit pattern in a short
static __device__ inline short bf16s(float x) {
    union { float f; unsigned u; } v; v.f = x;
    unsigned r = v.u + 0x7fffu + ((v.u >> 16) & 1u);
    return (short)(r >> 16);
}

// exp2 via the HW transcendental (1 inst)
#if __has_builtin(__builtin_amdgcn_exp2f)
static __device__ inline float fexp2(float x) { return __builtin_amdgcn_exp2f(x); }
#else
static __device__ inline float fexp2(float x) { return __builtin_exp2f(x); }
#endif

// pack two fp32 into bf16x2 via v_cvt_pk_bf16_f32
static __device__ inline __hip_bfloat162 pk2(float a, float b) {
    float2 t; t.x = a; t.y = b;
    return __float22bfloat162_rn(t);
}

#define QSCALE 0.36067376022224085f   /* 0.25 * log2(e) */

// ---------------------------------------------------------------------------
// Kernel 1: pack win into bf16 K=256 complex-packed layout (precedes qkv).
// ---------------------------------------------------------------------------
__global__ void pack_win_kernel(
    const float* __restrict__ win_re, const float* __restrict__ win_im,
    short* __restrict__ Wp_re, short* __restrict__ Wp_im)
{
    int idx = blockIdx.x * 256 + threadIdx.x;   // [0, 384*128)
    int j = idx >> 7, e = idx & 127;
    float wr = win_re[idx], wi = win_im[idx];
    Wp_re[j*256 + e]       = bf16s(wr);
    Wp_re[j*256 + 128 + e] = bf16s(-wi);
    Wp_im[j*256 + e]       = bf16s(wi);
    Wp_im[j*256 + 128 + e] = bf16s(wr);
}

// ---------------------------------------------------------------------------
// Kernel 2: QKV projection (8 waves/block, 512 threads -> 16 waves/CU)
// PLUS piggy-backed fuse-weights blocks (independent of qkv; only feed
// outproj) so the wt@wout straggler hides under qkv instead of serializing.
//   blocks [0,512):   qkv t-tiles (wave handles 3 j-tiles x 2 halves)
//   blocks [512,544): Wfp fuse (512 threads each, idx = (bid-512)*512+tid)
//   block  544:       fused bias (threads 0..127)
// Outputs byte-identical to the round-1 verified kernels.
// ---------------------------------------------------------------------------
__global__ __launch_bounds__(512, 4) void qkv_fuse_kernel(
    const float* __restrict__ x_re, const float* __restrict__ x_im,
    const short* __restrict__ Wp_re, const short* __restrict__ Wp_im,
    const float* __restrict__ bin_re, const float* __restrict__ bin_im,
    const float* __restrict__ wout_re, const float* __restrict__ wout_im,
    const float* __restrict__ bout_re, const float* __restrict__ bout_im,
    const float* __restrict__ wt_re,   const float* __restrict__ wt_im,
    const float* __restrict__ bt_re,   const float* __restrict__ bt_im,
    short* __restrict__ Qpk, short* __restrict__ Kpk,
    short* __restrict__ Vtre, short* __restrict__ Vtim,
    short* __restrict__ Wfp_re, short* __restrict__ Wfp_im,
    float* __restrict__ bf_re, float* __restrict__ bf_im)
{
    int bid = blockIdx.x;
    int tid = threadIdx.x;

    if (bid < 512) {
        // ---- qkv ----
        int wave = tid >> 6, lane = tid & 63;
        int col  = lane & 15, quad = lane >> 4;
        int ttile = bid;
        int b  = ttile >> 6;
        int tb = (ttile & 63) * 16 + col;

        // X fragments for 8 k-tiles (per-wave copies; L1 hits across waves)
        short8 xf[8];
        #pragma unroll
        for (int kt = 0; kt < 8; ++kt) {
            const float* xs = (kt < 4) ? x_re : x_im;
            const float* p = &xs[((long)(b*E + (kt & 3)*32 + quad*8))*T + tb];
            float v0 = p[0], v1 = p[(long)T], v2 = p[2L*T], v3 = p[3L*T];
            float v4 = p[4L*T], v5 = p[5L*T], v6 = p[6L*T], v7 = p[7L*T];
            __hip_bfloat162* xp = (__hip_bfloat162*)&xf[kt];
            xp[0] = pk2(v0, v1); xp[1] = pk2(v2, v3);
            xp[2] = pk2(v4, v5); xp[3] = pk2(v6, v7);
        }

        const f32x4 zero = {0.f,0.f,0.f,0.f};

        #pragma unroll
        for (int half = 0; half < 2; ++half) {
            const short* Wsel = half ? Wp_im : Wp_re;
            const float* bias = half ? bin_im : bin_re;

            for (int ni = 0; ni < 3; ++ni) {
                int jt = wave * 3 + ni;            // [0,24): which*8 + h
                const short* wrow = &Wsel[(jt*16 + col)*256 + quad*8];
                f32x4 acc = zero;
                #pragma unroll
                for (int kt = 0; kt < 8; ++kt) {
                    short8 af = *(const short8*)(wrow + kt*32);
                    acc = __builtin_amdgcn_mfma_f32_16x16x32_bf16(af, xf[kt], acc, 0, 0, 0);
                }
                int which = jt >> 3;               // 0 q, 1 k, 2 v
                int h = jt & 7;
                float scale = (which == 0) ? QSCALE : 1.0f;
                f32x4 res;
                #pragma unroll
                for (int r = 0; r < 4; ++r) {
                    int jg = which*128 + h*16 + quad*4 + r;
                    res[r] = (acc[r] + bias[jg]) * scale;
                }
                long bh = b*H + h;
                if (which == 2) {
                    // V transposed + pi-interleaved: Vt[bh][dh][blk*32 + pos]
                    short* vt = half ? Vtim : Vtre;
                    int tloc = tb & 31, tblk = tb & ~31;
                    int u  = tloc & 15;
                    int kk = (u >> 2)*8 + (u & 3) + ((tloc >= 16) ? 4 : 0);
                    #pragma unroll
                    for (int r = 0; r < 4; ++r)
                        vt[(bh*DH + quad*4 + r)*T + tblk + kk] = bf16s(res[r]);
                } else {
                    short* qk = (which == 0) ? Qpk : Kpk;
                    short4s pk;
                    __hip_bfloat162* pp = (__hip_bfloat162*)&pk;
                    pp[0] = pk2(res[0], res[1]);
                    pp[1] = pk2(res[2], res[3]);
                    *(short4s*)&qk[(bh*T + tb)*32 + half*16 + quad*4] = pk;
                }
            }
        }
    } else if (bid < 544) {
        // ---- fuse output linears: wf = wt @ wout (complex) ----
        int idx = (bid - 512) * 512 + tid;        // [0, E*E)
        int j = idx >> 7, e = idx & 127;
        float ar = 0.f, ai = 0.f;
        for (int m = 0; m < E; ++m) {
            float tr = wt_re[j*E+m], ti = wt_im[j*E+m];
            float pr = wout_re[m*E+e], pi = wout_im[m*E+e];
            ar += tr*pr - ti*pi;
            ai += tr*pi + ti*pr;
        }
        Wfp_re[j*256 + e]       = bf16s(ar);
        Wfp_re[j*256 + 128 + e] = bf16s(-ai);
        Wfp_im[j*256 + e]       = bf16s(ai);
        Wfp_im[j*256 + 128 + e] = bf16s(ar);
    } else {
        // ---- fused bias: bf = wt @ bout + bt ----
        if (tid < E) {
            float br = bt_re[tid], bi = bt_im[tid];
            for (int m = 0; m < E; ++m) {
                float tr = wt_re[tid*E+m], ti = wt_im[tid*E+m];
                br += tr*bout_re[m] - ti*bout_im[m];
                bi += tr*bout_im[m] + ti*bout_re[m];
            }
            bf_re[tid] = br; bf_im[tid] = bi;
        }
    }
}

// ---------------------------------------------------------------------------
// Kernel 3: MFMA flash attention -- 16 queries/wave, grid 1024 (16 qt x 64
// bh) -> 4 blocks/CU = 16 waves/CU (was 8). Round-4 counters showed ~90%
// latency stall at 2 waves/SIMD; halving the per-wave dependent chain and
// doubling TLP attacks that directly. Blocks sharing bh sit on one XCD
// (bid stride 64 = 0 mod 8) so the doubled K/V reads are L2-hits.
// Per-STEP: 2 QK MFMA -> 8 exp2 -> 3 PV MFMA; distance-2 prefetch; setprio.
// ---------------------------------------------------------------------------
__global__ __launch_bounds__(256, 4) void attn_mfma_kernel(
    const short* __restrict__ Qpk, const short* __restrict__ Kpk,
    const short* __restrict__ Vtre, const short* __restrict__ Vtim,
    short* __restrict__ Opk)
{
    int id   = blockIdx.x;             // [0, 1024)
    int bh   = id & 63;
    int qt   = id >> 6;                // [0, 16)
    int tid  = threadIdx.x;
    int wave = tid >> 6;
    int lane = tid & 63;
    int col  = lane & 15;
    int quad = lane >> 4;

    long kq_base = (long)bh * T * 32;
    int qbase = qt * 64 + wave * 16;

    short8 qf = *(const short8*)&Qpk[kq_base + (long)(qbase + col)*32 + quad*8];

    const short* kp  = &Kpk[kq_base + col*32 + quad*8];
    const short* vrp = &Vtre[(long)bh*DH*T + (long)col*T + quad*8];
    const short* vip = &Vtim[(long)bh*DH*T + (long)col*T + quad*8];

    short8 ones;
    #pragma unroll
    for (int i = 0; i < 8; ++i) ones[i] = (short)0x3F80;   // bf16 1.0

    f32x4 or_ = {0,0,0,0}, oi = {0,0,0,0}, l = {0,0,0,0};
    const f32x4 zero = {0.f,0.f,0.f,0.f};

    auto STEP = [&](short8 kf0, short8 kf1, short8 vr, short8 vi) {
        __builtin_amdgcn_s_setprio(1);
        f32x4 s0 = __builtin_amdgcn_mfma_f32_16x16x32_bf16(kf0, qf, zero, 0, 0, 0);
        f32x4 s1 = __builtin_amdgcn_mfma_f32_16x16x32_bf16(kf1, qf, zero, 0, 0, 0);
        __builtin_amdgcn_s_setprio(0);

        short8 pf;
        {
            __hip_bfloat162* pa = (__hip_bfloat162*)&pf;
            pa[0] = pk2(fexp2(s0[0]), fexp2(s0[1]));
            pa[1] = pk2(fexp2(s0[2]), fexp2(s0[3]));
            pa[2] = pk2(fexp2(s1[0]), fexp2(s1[1]));
            pa[3] = pk2(fexp2(s1[2]), fexp2(s1[3]));
        }

        __builtin_amdgcn_s_setprio(1);
        or_ = __builtin_amdgcn_mfma_f32_16x16x32_bf16(vr, pf, or_, 0, 0, 0);
        oi  = __builtin_amdgcn_mfma_f32_16x16x32_bf16(vi, pf, oi, 0, 0, 0);
        l   = __builtin_amdgcn_mfma_f32_16x16x32_bf16(ones, pf, l, 0, 0, 0);
        __builtin_amdgcn_s_setprio(0);
    };

    // prologue: tiles 0 and 1 in flight (distance-2 pipeline)
    short8 k0A = *(const short8*)kp;
    short8 k1A = *(const short8*)(kp + 512);
    short8 vrA = *(const short8*)vrp;
    short8 viA = *(const short8*)vip;
    short8 k0B = *(const short8*)(kp + 1024);
    short8 k1B = *(const short8*)(kp + 1536);
    short8 vrB = *(const short8*)(vrp + 32);
    short8 viB = *(const short8*)(vip + 32);
    kp += 2048; vrp += 64; vip += 64;

    for (int i = 0; i < 32; i += 2) {
        // prefetch tile i+2 (tail over-reads land in adjacent ws, unused)
        short8 k0n = *(const short8*)kp;
        short8 k1n = *(const short8*)(kp + 512);
        short8 vrn = *(const short8*)vrp;
        short8 vin = *(const short8*)vip;
        kp += 1024; vrp += 32; vip += 32;

        STEP(k0A, k1A, vrA, viA);                    // tile i
        k0A = k0n; k1A = k1n; vrA = vrn; viA = vin;

        // prefetch tile i+3
        k0n = *(const short8*)kp;
        k1n = *(const short8*)(kp + 512);
        vrn = *(const short8*)vrp;
        vin = *(const short8*)vip;
        kp += 1024; vrp += 32; vip += 32;

        STEP(k0B, k1B, vrB, viB);                    // tile i+1
        k0B = k0n; k1B = k1n; vrB = vrn; viB = vin;
    }

    int b = bh >> 3, h = bh & 7;
    float inv = 1.0f / l[0];

    long orow = ((long)(b*T + qbase + col))*256 + h*16 + quad*4;
    short4s pr, pi_;
    __hip_bfloat162* a = (__hip_bfloat162*)&pr;
    a[0] = pk2(or_[0]*inv, or_[1]*inv);
    a[1] = pk2(or_[2]*inv, or_[3]*inv);
    __hip_bfloat162* c = (__hip_bfloat162*)&pi_;
    c[0] = pk2(oi[0]*inv, oi[1]*inv);
    c[1] = pk2(oi[2]*inv, oi[3]*inv);
    *(short4s*)&Opk[orow]       = pr;
    *(short4s*)&Opk[orow + 128] = pi_;
}

// ---------------------------------------------------------------------------
// Kernel 4: MFMA output projection; grid 1024 (t-tile x j-half) -> 4
// blocks/CU. Each wave handles 2 j-tiles; Opk row reads duplicated x2
// (L2-resident). Store formula identical to verified version.
// ---------------------------------------------------------------------------
__global__ __launch_bounds__(256, 4) void outproj_mfma_kernel(
    const short* __restrict__ Opk,
    const short* __restrict__ Wfp_re, const short* __restrict__ Wfp_im,
    const float* __restrict__ bf_re, const float* __restrict__ bf_im,
    float* __restrict__ out)
{
    int tid  = threadIdx.x;
    int wave = tid >> 6, lane = tid & 63;
    int col  = lane & 15, quad = lane >> 4;
    int jhalf = blockIdx.x & 1;
    int ttile = blockIdx.x >> 1;       // [0,512)
    int b  = ttile >> 6;
    int tb = (ttile & 63) * 16 + col;
    long trow = (long)b*T + tb;

    short8 xf[8];
    #pragma unroll
    for (int kt = 0; kt < 8; ++kt)
        xf[kt] = *(const short8*)&Opk[trow*256 + kt*32 + quad*8];

    const f32x4 zero = {0.f,0.f,0.f,0.f};
    #pragma unroll
    for (int ni = 0; ni < 2; ++ni) {
        int nt = jhalf*8 + wave*2 + ni;    // [0,16)
        int is_im = nt >= 8;
        int jt = is_im ? nt - 8 : nt;      // [0,8)
        const short* Wsel = is_im ? Wfp_im : Wfp_re;
        const short* wrow = &Wsel[(jt*16 + col)*256 + quad*8];
        f32x4 acc = zero;
        #pragma unroll
        for (int kt = 0; kt < 8; ++kt) {
            short8 af = *(const short8*)(wrow + kt*32);
            acc = __builtin_amdgcn_mfma_f32_16x16x32_bf16(af, xf[kt], acc, 0, 0, 0);
        }
        const float* bias = is_im ? bf_im : bf_re;
        long part = is_im ? (long)B*E*T : 0;
        #pragma unroll
        for (int r = 0; r < 4; ++r) {
            int j = jt*16 + quad*4 + r;
            out[part + ((long)(b*E + j))*T + tb] = acc[r] + bias[j];
        }
    }
}

// ---------------------------------------------------------------------------
extern "C" void kernel_launch(void* const* d_in, const int* in_sizes, int n_in,
                              void* d_out, int out_size, void* d_ws, size_t ws_size,
                              hipStream_t stream)
{
    const float* x_re    = (const float*)d_in[0];
    const float* x_im    = (const float*)d_in[1];
    const float* win_re  = (const float*)d_in[2];
    const float* win_im  = (const float*)d_in[3];
    const float* bin_re  = (const float*)d_in[4];
    const float* bin_im  = (const float*)d_in[5];
    const float* wout_re = (const float*)d_in[6];
    const float* wout_im = (const float*)d_in[7];
    const float* bout_re = (const float*)d_in[8];
    const float* bout_im = (const float*)d_in[9];
    const float* wt_re   = (const float*)d_in[10];
    const float* wt_im   = (const float*)d_in[11];
    const float* bt_re   = (const float*)d_in[12];
    const float* bt_im   = (const float*)d_in[13];
    float* out = (float*)d_out;

    // workspace layout (shorts/floats)
    short* Qpk  = (short*)d_ws;                       // 64*1024*32 = 2M shorts
    short* Kpk  = Qpk + (long)B*H*T*32;
    short* Vtre = Kpk + (long)B*H*T*32;               // 64*16*1024 = 1M shorts
    short* Vtim = Vtre + (long)B*H*DH*T;
    short* Opk  = Vtim + (long)B*H*DH*T;              // 8*1024*256 = 2M shorts
    short* Wp_re  = Opk + (long)B*T*256;
    short* Wp_im  = Wp_re + E3*256;
    short* Wfp_re = Wp_im + E3*256;
    short* Wfp_im = Wfp_re + E*256;
    float* bf_re  = (float*)(Wfp_im + E*256);
    float* bf_im  = bf_re + E;

    pack_win_kernel<<<dim3(E3*E/256), dim3(256), 0, stream>>>(
        win_re, win_im, Wp_re, Wp_im);

    qkv_fuse_kernel<<<dim3(545), dim3(512), 0, stream>>>(
        x_re, x_im, Wp_re, Wp_im, bin_re, bin_im,
        wout_re, wout_im, bout_re, bout_im,
        wt_re, wt_im, bt_re, bt_im,
        Qpk, Kpk, Vtre, Vtim,
        Wfp_re, Wfp_im, bf_re, bf_im);

    attn_mfma_kernel<<<dim3(16 * 64), dim3(256), 0, stream>>>(
        Qpk, Kpk, Vtre, Vtim, Opk);

    outproj_mfma_kernel<<<dim3(1024), dim3(256), 0, stream>>>(
        Opk, Wfp_re, Wfp_im, bf_re, bf_im, out);
}

// Round 6
// 142.276 us; speedup vs baseline: 2.9573x; 1.2916x over previous
//
#include <hip/hip_runtime.h>
#include <hip/hip_bf16.h>

#define B 8
#define T 1024
#define E 128
#define H 8
#define DH 16
#define E3 384

typedef __attribute__((ext_vector_type(8))) short short8;
typedef __attribute__((ext_vector_type(4))) short short4s;
typedef __attribute__((ext_vector_type(4))) float f32x4;

// fp32 -> bf16 (round-to-nearest-even), bit pattern in a short
static __device__ inline short bf16s(float x) {
    union { float f; unsigned u; } v; v.f = x;
    unsigned r = v.u + 0x7fffu + ((v.u >> 16) & 1u);
    return (short)(r >> 16);
}

// exp2 via the HW transcendental (1 inst)
#if __has_builtin(__builtin_amdgcn_exp2f)
static __device__ inline float fexp2(float x) { return __builtin_amdgcn_exp2f(x); }
#else
static __device__ inline float fexp2(float x) { return __builtin_exp2f(x); }
#endif

// pack two fp32 into bf16x2 via v_cvt_pk_bf16_f32
static __device__ inline __hip_bfloat162 pk2(float a, float b) {
    float2 t; t.x = a; t.y = b;
    return __float22bfloat162_rn(t);
}

// async global->LDS, 16B per lane: LDS gets lane l's data at base + l*16
static __device__ inline void stage16(const void* g, void* l) {
    __builtin_amdgcn_global_load_lds(
        (const __attribute__((address_space(1))) void*)g,
        (__attribute__((address_space(3))) void*)l,
        16, 0, 0);
}

#define QSCALE 0.36067376022224085f   /* 0.25 * log2(e) */

// ---------------------------------------------------------------------------
// Kernel 1: pack win into bf16 K=256 complex-packed layout (precedes qkv).
// ---------------------------------------------------------------------------
__global__ void pack_win_kernel(
    const float* __restrict__ win_re, const float* __restrict__ win_im,
    short* __restrict__ Wp_re, short* __restrict__ Wp_im)
{
    int idx = blockIdx.x * 256 + threadIdx.x;   // [0, 384*128)
    int j = idx >> 7, e = idx & 127;
    float wr = win_re[idx], wi = win_im[idx];
    Wp_re[j*256 + e]       = bf16s(wr);
    Wp_re[j*256 + 128 + e] = bf16s(-wi);
    Wp_im[j*256 + e]       = bf16s(wi);
    Wp_im[j*256 + 128 + e] = bf16s(wr);
}

// ---------------------------------------------------------------------------
// Kernel 2: QKV projection -- round-1 verified 256-thread structure (4 waves,
// 6 j-tiles each, xf built once per block) PLUS piggy-backed fuse-weights
// blocks (independent; only feed outproj) so the wt@wout straggler hides
// under qkv instead of serializing in its own launch.
//   blocks [0,512):   qkv t-tiles
//   blocks [512,576): Wfp fuse (idx = (bid-512)*256 + tid)
//   block  576:       fused bias (threads 0..127)
// ---------------------------------------------------------------------------
__global__ __launch_bounds__(256) void qkv_fuse_kernel(
    const float* __restrict__ x_re, const float* __restrict__ x_im,
    const short* __restrict__ Wp_re, const short* __restrict__ Wp_im,
    const float* __restrict__ bin_re, const float* __restrict__ bin_im,
    const float* __restrict__ wout_re, const float* __restrict__ wout_im,
    const float* __restrict__ bout_re, const float* __restrict__ bout_im,
    const float* __restrict__ wt_re,   const float* __restrict__ wt_im,
    const float* __restrict__ bt_re,   const float* __restrict__ bt_im,
    short* __restrict__ Qpk, short* __restrict__ Kpk,
    short* __restrict__ Vtre, short* __restrict__ Vtim,
    short* __restrict__ Wfp_re, short* __restrict__ Wfp_im,
    float* __restrict__ bf_re, float* __restrict__ bf_im)
{
    int bid = blockIdx.x;
    int tid = threadIdx.x;

    if (bid < 512) {
        // ---- qkv (byte-identical to round-1 verified kernel) ----
        int wave = tid >> 6, lane = tid & 63;
        int col  = lane & 15, quad = lane >> 4;
        int ttile = bid;
        int b  = ttile >> 6;
        int tb = (ttile & 63) * 16 + col;

        short8 xf[8];
        #pragma unroll
        for (int kt = 0; kt < 8; ++kt) {
            const float* xs = (kt < 4) ? x_re : x_im;
            const float* p = &xs[((long)(b*E + (kt & 3)*32 + quad*8))*T + tb];
            float v0 = p[0], v1 = p[(long)T], v2 = p[2L*T], v3 = p[3L*T];
            float v4 = p[4L*T], v5 = p[5L*T], v6 = p[6L*T], v7 = p[7L*T];
            __hip_bfloat162* xp = (__hip_bfloat162*)&xf[kt];
            xp[0] = pk2(v0, v1); xp[1] = pk2(v2, v3);
            xp[2] = pk2(v4, v5); xp[3] = pk2(v6, v7);
        }

        const f32x4 zero = {0.f,0.f,0.f,0.f};

        #pragma unroll
        for (int half = 0; half < 2; ++half) {
            const short* Wsel = half ? Wp_im : Wp_re;
            const float* bias = half ? bin_im : bin_re;

            for (int ni = 0; ni < 6; ++ni) {
                int jt = wave * 6 + ni;            // [0,24): which*8 + h
                const short* wrow = &Wsel[(jt*16 + col)*256 + quad*8];
                f32x4 acc = zero;
                #pragma unroll
                for (int kt = 0; kt < 8; ++kt) {
                    short8 af = *(const short8*)(wrow + kt*32);
                    acc = __builtin_amdgcn_mfma_f32_16x16x32_bf16(af, xf[kt], acc, 0, 0, 0);
                }
                int which = jt >> 3;               // 0 q, 1 k, 2 v
                int h = jt & 7;
                float scale = (which == 0) ? QSCALE : 1.0f;
                f32x4 res;
                #pragma unroll
                for (int r = 0; r < 4; ++r) {
                    int jg = which*128 + h*16 + quad*4 + r;
                    res[r] = (acc[r] + bias[jg]) * scale;
                }
                long bh = b*H + h;
                if (which == 2) {
                    // V transposed + pi-interleaved: Vt[bh][dh][blk*32 + pos]
                    short* vt = half ? Vtim : Vtre;
                    int tloc = tb & 31, tblk = tb & ~31;
                    int u  = tloc & 15;
                    int kk = (u >> 2)*8 + (u & 3) + ((tloc >= 16) ? 4 : 0);
                    #pragma unroll
                    for (int r = 0; r < 4; ++r)
                        vt[(bh*DH + quad*4 + r)*T + tblk + kk] = bf16s(res[r]);
                } else {
                    short* qk = (which == 0) ? Qpk : Kpk;
                    short4s pk;
                    __hip_bfloat162* pp = (__hip_bfloat162*)&pk;
                    pp[0] = pk2(res[0], res[1]);
                    pp[1] = pk2(res[2], res[3]);
                    *(short4s*)&qk[(bh*T + tb)*32 + half*16 + quad*4] = pk;
                }
            }
        }
    } else if (bid < 576) {
        // ---- fuse output linears: wf = wt @ wout (complex) ----
        int idx = (bid - 512) * 256 + tid;        // [0, E*E)
        int j = idx >> 7, e = idx & 127;
        float ar = 0.f, ai = 0.f;
        for (int m = 0; m < E; ++m) {
            float tr = wt_re[j*E+m], ti = wt_im[j*E+m];
            float pr = wout_re[m*E+e], pi = wout_im[m*E+e];
            ar += tr*pr - ti*pi;
            ai += tr*pi + ti*pr;
        }
        Wfp_re[j*256 + e]       = bf16s(ar);
        Wfp_re[j*256 + 128 + e] = bf16s(-ai);
        Wfp_im[j*256 + e]       = bf16s(ai);
        Wfp_im[j*256 + 128 + e] = bf16s(ar);
    } else {
        // ---- fused bias: bf = wt @ bout + bt ----
        if (tid < E) {
            float br = bt_re[tid], bi = bt_im[tid];
            for (int m = 0; m < E; ++m) {
                float tr = wt_re[tid*E+m], ti = wt_im[tid*E+m];
                br += tr*bout_re[m] - ti*bout_im[m];
                bi += tr*bout_im[m] + ti*bout_re[m];
            }
            bf_re[tid] = br; bf_im[tid] = bi;
        }
    }
}

// ---------------------------------------------------------------------------
// Kernel 3: MFMA flash attention with LDS-shared K/V.
// Round-5 counters: attn 50.6us, MfmaUtil 7.4%, 79% stall -> every wave was
// redundantly streaming the SAME 128KB K/V as its 3 siblings. Now the 4
// components (kf0,kf1,vr,vi -- identical across waves) are staged ONCE per
// block: wave w issues one global_load_lds for component w using the
// original per-lane global addresses; LDS holds lane l's data at l*16, read
// back at l*16 -> bit-identical fragments. Double-buffered 8KB LDS, one
// __syncthreads per tile (its vmcnt-drain covers the single in-flight
// stage issued a full compute-phase earlier). Loads/block-iter: 16 -> 4.
// Structure otherwise identical to round-1 verified attn (32q/wave, A/B
// fragments, grid 512 = 8 qchunk x 64 bh; same-bh blocks share an XCD).
// ---------------------------------------------------------------------------
__global__ __launch_bounds__(256, 2) void attn_mfma_kernel(
    const short* __restrict__ Qpk, const short* __restrict__ Kpk,
    const short* __restrict__ Vtre, const short* __restrict__ Vtim,
    short* __restrict__ Opk)
{
    __shared__ short lbuf[2][4][512];   // [parity][component][1KB]

    int id   = blockIdx.x;
    int bh   = id & 63;
    int q0   = (id >> 6) * 128;
    int tid  = threadIdx.x;
    int wave = tid >> 6;
    int lane = tid & 63;
    int col  = lane & 15;
    int quad = lane >> 4;

    long kq_base = (long)bh * T * 32;
    int qbase = q0 + wave * 32;

    short8 qfA = *(const short8*)&Qpk[kq_base + (long)(qbase + col)*32 + quad*8];
    short8 qfB = *(const short8*)&Qpk[kq_base + (long)(qbase + 16 + col)*32 + quad*8];

    // this wave's staging component: 0=kf0, 1=kf1, 2=vr, 3=vi
    const short* gsrc;
    int gstep;
    if (wave == 0)      { gsrc = &Kpk[kq_base + col*32 + quad*8];              gstep = 1024; }
    else if (wave == 1) { gsrc = &Kpk[kq_base + 512 + col*32 + quad*8];        gstep = 1024; }
    else if (wave == 2) { gsrc = &Vtre[(long)bh*DH*T + (long)col*T + quad*8];  gstep = 32; }
    else                { gsrc = &Vtim[(long)bh*DH*T + (long)col*T + quad*8];  gstep = 32; }

    short8 ones;
    #pragma unroll
    for (int i = 0; i < 8; ++i) ones[i] = (short)0x3F80;   // bf16 1.0

    f32x4 oAr = {0,0,0,0}, oAi = {0,0,0,0}, lA = {0,0,0,0};
    f32x4 oBr = {0,0,0,0}, oBi = {0,0,0,0}, lB = {0,0,0,0};
    const f32x4 zero = {0.f,0.f,0.f,0.f};

    // prologue: stage tile 0 into parity 0
    stage16(gsrc, &lbuf[0][wave][0]);
    gsrc += gstep;
    __syncthreads();                    // tile 0 in LDS (vmcnt drained)

    for (int i = 0; i < 32; ++i) {
        int p = i & 1;
        // stage tile i+1 into the other buffer (overwrites tile i-1, whose
        // reads completed before the previous barrier). Tile-32 over-read
        // lands in LDS unused -- global side stays inside the workspace.
        stage16(gsrc, &lbuf[p^1][wave][0]);
        gsrc += gstep;

        // fragments from LDS (bit-identical to the original global loads)
        short8 kf0 = *(const short8*)&lbuf[p][0][lane*8];
        short8 kf1 = *(const short8*)&lbuf[p][1][lane*8];
        short8 vr  = *(const short8*)&lbuf[p][2][lane*8];
        short8 vi  = *(const short8*)&lbuf[p][3][lane*8];

        __builtin_amdgcn_s_setprio(1);
        f32x4 sA0 = __builtin_amdgcn_mfma_f32_16x16x32_bf16(kf0, qfA, zero, 0, 0, 0);
        f32x4 sA1 = __builtin_amdgcn_mfma_f32_16x16x32_bf16(kf1, qfA, zero, 0, 0, 0);
        f32x4 sB0 = __builtin_amdgcn_mfma_f32_16x16x32_bf16(kf0, qfB, zero, 0, 0, 0);
        f32x4 sB1 = __builtin_amdgcn_mfma_f32_16x16x32_bf16(kf1, qfB, zero, 0, 0, 0);
        __builtin_amdgcn_s_setprio(0);

        short8 pfA, pfB;
        {
            __hip_bfloat162* pa = (__hip_bfloat162*)&pfA;
            pa[0] = pk2(fexp2(sA0[0]), fexp2(sA0[1]));
            pa[1] = pk2(fexp2(sA0[2]), fexp2(sA0[3]));
            pa[2] = pk2(fexp2(sA1[0]), fexp2(sA1[1]));
            pa[3] = pk2(fexp2(sA1[2]), fexp2(sA1[3]));
            __hip_bfloat162* pb = (__hip_bfloat162*)&pfB;
            pb[0] = pk2(fexp2(sB0[0]), fexp2(sB0[1]));
            pb[1] = pk2(fexp2(sB0[2]), fexp2(sB0[3]));
            pb[2] = pk2(fexp2(sB1[0]), fexp2(sB1[1]));
            pb[3] = pk2(fexp2(sB1[2]), fexp2(sB1[3]));
        }

        __builtin_amdgcn_s_setprio(1);
        oAr = __builtin_amdgcn_mfma_f32_16x16x32_bf16(vr, pfA, oAr, 0, 0, 0);
        oAi = __builtin_amdgcn_mfma_f32_16x16x32_bf16(vi, pfA, oAi, 0, 0, 0);
        lA  = __builtin_amdgcn_mfma_f32_16x16x32_bf16(ones, pfA, lA, 0, 0, 0);
        oBr = __builtin_amdgcn_mfma_f32_16x16x32_bf16(vr, pfB, oBr, 0, 0, 0);
        oBi = __builtin_amdgcn_mfma_f32_16x16x32_bf16(vi, pfB, oBi, 0, 0, 0);
        lB  = __builtin_amdgcn_mfma_f32_16x16x32_bf16(ones, pfB, lB, 0, 0, 0);
        __builtin_amdgcn_s_setprio(0);

        __syncthreads();   // drains this iter's stage; syncs buf reads
    }

    int b = bh >> 3, h = bh & 7;
    float invA = 1.0f / lA[0];
    float invB = 1.0f / lB[0];

    long orowA = ((long)(b*T + qbase + col))*256 + h*16 + quad*4;
    {
        short4s pr, pi_;
        __hip_bfloat162* a = (__hip_bfloat162*)&pr;
        a[0] = pk2(oAr[0]*invA, oAr[1]*invA);
        a[1] = pk2(oAr[2]*invA, oAr[3]*invA);
        __hip_bfloat162* c = (__hip_bfloat162*)&pi_;
        c[0] = pk2(oAi[0]*invA, oAi[1]*invA);
        c[1] = pk2(oAi[2]*invA, oAi[3]*invA);
        *(short4s*)&Opk[orowA]       = pr;
        *(short4s*)&Opk[orowA + 128] = pi_;
    }
    long orowB = orowA + 16L*256;
    {
        short4s pr, pi_;
        __hip_bfloat162* a = (__hip_bfloat162*)&pr;
        a[0] = pk2(oBr[0]*invB, oBr[1]*invB);
        a[1] = pk2(oBr[2]*invB, oBr[3]*invB);
        __hip_bfloat162* c = (__hip_bfloat162*)&pi_;
        c[0] = pk2(oBi[0]*invB, oBi[1]*invB);
        c[1] = pk2(oBi[2]*invB, oBi[3]*invB);
        *(short4s*)&Opk[orowB]       = pr;
        *(short4s*)&Opk[orowB + 128] = pi_;
    }
}

// ---------------------------------------------------------------------------
// Kernel 4: MFMA output projection (round-1 verified version, grid 512).
// ---------------------------------------------------------------------------
__global__ __launch_bounds__(256) void outproj_mfma_kernel(
    const short* __restrict__ Opk,
    const short* __restrict__ Wfp_re, const short* __restrict__ Wfp_im,
    const float* __restrict__ bf_re, const float* __restrict__ bf_im,
    float* __restrict__ out)
{
    int tid  = threadIdx.x;
    int wave = tid >> 6, lane = tid & 63;
    int col  = lane & 15, quad = lane >> 4;
    int ttile = blockIdx.x;            // [0,512)
    int b  = ttile >> 6;
    int tb = (ttile & 63) * 16 + col;
    long trow = (long)b*T + tb;

    short8 xf[8];
    #pragma unroll
    for (int kt = 0; kt < 8; ++kt)
        xf[kt] = *(const short8*)&Opk[trow*256 + kt*32 + quad*8];

    const f32x4 zero = {0.f,0.f,0.f,0.f};
    #pragma unroll
    for (int ni = 0; ni < 4; ++ni) {
        int nt = wave * 4 + ni;            // [0,16)
        int is_im = nt >= 8;
        int jt = is_im ? nt - 8 : nt;      // [0,8)
        const short* Wsel = is_im ? Wfp_im : Wfp_re;
        const short* wrow = &Wsel[(jt*16 + col)*256 + quad*8];
        f32x4 acc = zero;
        #pragma unroll
        for (int kt = 0; kt < 8; ++kt) {
            short8 af = *(const short8*)(wrow + kt*32);
            acc = __builtin_amdgcn_mfma_f32_16x16x32_bf16(af, xf[kt], acc, 0, 0, 0);
        }
        const float* bias = is_im ? bf_im : bf_re;
        long part = is_im ? (long)B*E*T : 0;
        #pragma unroll
        for (int r = 0; r < 4; ++r) {
            int j = jt*16 + quad*4 + r;
            out[part + ((long)(b*E + j))*T + tb] = acc[r] + bias[j];
        }
    }
}

// ---------------------------------------------------------------------------
extern "C" void kernel_launch(void* const* d_in, const int* in_sizes, int n_in,
                              void* d_out, int out_size, void* d_ws, size_t ws_size,
                              hipStream_t stream)
{
    const float* x_re    = (const float*)d_in[0];
    const float* x_im    = (const float*)d_in[1];
    const float* win_re  = (const float*)d_in[2];
    const float* win_im  = (const float*)d_in[3];
    const float* bin_re  = (const float*)d_in[4];
    const float* bin_im  = (const float*)d_in[5];
    const float* wout_re = (const float*)d_in[6];
    const float* wout_im = (const float*)d_in[7];
    const float* bout_re = (const float*)d_in[8];
    const float* bout_im = (const float*)d_in[9];
    const float* wt_re   = (const float*)d_in[10];
    const float* wt_im   = (const float*)d_in[11];
    const float* bt_re   = (const float*)d_in[12];
    const float* bt_im   = (const float*)d_in[13];
    float* out = (float*)d_out;

    // workspace layout (shorts/floats)
    short* Qpk  = (short*)d_ws;                       // 64*1024*32 = 2M shorts
    short* Kpk  = Qpk + (long)B*H*T*32;
    short* Vtre = Kpk + (long)B*H*T*32;               // 64*16*1024 = 1M shorts
    short* Vtim = Vtre + (long)B*H*DH*T;
    short* Opk  = Vtim + (long)B*H*DH*T;              // 8*1024*256 = 2M shorts
    short* Wp_re  = Opk + (long)B*T*256;
    short* Wp_im  = Wp_re + E3*256;
    short* Wfp_re = Wp_im + E3*256;
    short* Wfp_im = Wfp_re + E*256;
    float* bf_re  = (float*)(Wfp_im + E*256);
    float* bf_im  = bf_re + E;

    pack_win_kernel<<<dim3(E3*E/256), dim3(256), 0, stream>>>(
        win_re, win_im, Wp_re, Wp_im);

    qkv_fuse_kernel<<<dim3(577), dim3(256), 0, stream>>>(
        x_re, x_im, Wp_re, Wp_im, bin_re, bin_im,
        wout_re, wout_im, bout_re, bout_im,
        wt_re, wt_im, bt_re, bt_im,
        Qpk, Kpk, Vtre, Vtim,
        Wfp_re, Wfp_im, bf_re, bf_im);

    attn_mfma_kernel<<<dim3(8 * 64), dim3(256), 0, stream>>>(
        Qpk, Kpk, Vtre, Vtim, Opk);

    outproj_mfma_kernel<<<dim3(512), dim3(256), 0, stream>>>(
        Opk, Wfp_re, Wfp_im, bf_re, bf_im, out);
}